// Round 5
// baseline (544.593 us; speedup 1.0000x reference)
//
#include <hip/hip_runtime.h>
#include <math.h>

#define B_  2
#define D_  1536
#define L_  2048
#define N_  16
#define NH  8                 // states per half-wave group
#define LC  128               // chunk length along L (32 segs x 4 elems)
#define NCHUNK (L_ / LC)      // 16 (8 per wave)
#define NCH (B_ * D_)         // 3072 channels
#define LOG2E 1.4426950408889634f
#define LN2   0.6931471805599453f

typedef float f4 __attribute__((ext_vector_type(4)));
typedef float f8 __attribute__((ext_vector_type(8)));

__device__ __forceinline__ float exp2f_(float v) { return __builtin_amdgcn_exp2f(v); }
__device__ __forceinline__ float log2f_(float v) { return __builtin_amdgcn_logf(v); }
__device__ __forceinline__ float rcpf_(float v)  { return __builtin_amdgcn_rcpf(v); }

__device__ __forceinline__ float softplus_f(float v) {
    float t = exp2f_(v * LOG2E);                   // e^v
    float r = LN2 * log2f_(1.0f + t);              // ln(1+e^v)
    return (v > 20.0f) ? v : r;
}
__device__ __forceinline__ f8 splat8(float v) { f8 r = {v,v,v,v,v,v,v,v}; return r; }
__device__ __forceinline__ f8 exp2v8(f8 a) {
    f8 r;
    r[0]=exp2f_(a[0]); r[1]=exp2f_(a[1]); r[2]=exp2f_(a[2]); r[3]=exp2f_(a[3]);
    r[4]=exp2f_(a[4]); r[5]=exp2f_(a[5]); r[6]=exp2f_(a[6]); r[7]=exp2f_(a[7]);
    return r;
}
__device__ __forceinline__ float dot8(f8 a, f8 b) {
    float p0 = fmaf(a[0], b[0], a[1]*b[1]);
    float p1 = fmaf(a[2], b[2], a[3]*b[3]);
    float p2 = fmaf(a[4], b[4], a[5]*b[5]);
    float p3 = fmaf(a[6], b[6], a[7]*b[7]);
    return (p0 + p1) + (p2 + p3);
}

#define DPP_ROW_SHR(N) (0x110 + (N))
#define DPP_ROW_BCAST15 0x142
#define DPP_WAVE_SHR1   0x138
template<int CTRL, int RMASK>
__device__ __forceinline__ float updpp(float old, float v) {
    return __int_as_float(__builtin_amdgcn_update_dpp(
        __float_as_int(old), __float_as_int(v), CTRL, RMASK, 0xF, false));
}
template<int CTRL, int RMASK>
__device__ __forceinline__ float dpp0(float v) {
    return __int_as_float(__builtin_amdgcn_update_dpp(
        0, __float_as_int(v), CTRL, RMASK, 0xF, true));
}

// Round 5: 2-wave chunk-alternating pipeline.  One block (128 thr) = one
// channel; wave w owns chunks c with c%2==w and computes them COMPLETELY
// (identical math to round 4) — instruction count and HBM traffic unchanged
// vs the 77us 1-wave version, but waves/SIMD 3 -> 6 (fixing round-1's flaws:
// that attempt duplicated dt/exp work per wave and doubled delta/x traffic).
// The serial carry crosses waves through a 16-float LDS slot; 2 barriers per
// iteration, uniform count.  Everything except fold+pass2 is carry-
// independent and runs concurrently in both waves.
//
// Cross-barrier liveness control (round-3 spill lesson: count live regs AT
// the barrier, loads cannot sink across __syncthreads):
//   y_j = <C_j*F_j, h_in> + <C_j, S_j>   (j=0..2; y3 = <C3, hincv>)
// FRONT computes the carry-independent dots y_j0 (3 scalars) and G_j=C_j*F_j
// (24 regs); S0-2/F0-2 and the Cv loads die inside FRONT.  Live across the
// barriers: G0-2(24) + SC3(8) + F3/S3(16, die at fold) + y_j0(3) + xv(4) +
// A2v(8) ~ 65-70 -> fits the 85-reg cap of __launch_bounds__(128,6).
// z-load and the next-chunk prefetch (delta/x/B for c+2) sit in BACK.
__global__ __launch_bounds__(128, 6)
void ssm_scan_kernel(const float* __restrict__ x,
                     const float* __restrict__ delta,
                     const float* __restrict__ A,
                     const float* __restrict__ Bm,
                     const float* __restrict__ Cm,
                     const float* __restrict__ Dv,
                     const float* __restrict__ z,
                     const float* __restrict__ dbias,
                     float* __restrict__ out)
{
    const int tid  = threadIdx.x;      // 0..127
    const int lane = tid & 63;
    const int s    = lane & 31;
    const int g    = (lane >> 5) & 1;  // half-wave state group
    const int w    = tid >> 6;         // wave id: chunk parity owner
    const int ch   = blockIdx.x;       // one channel per block
    const int b    = ch / D_;
    const int d    = ch - b * D_;

    __shared__ alignas(16) float carrybuf[2][N_];  // [chunk parity][16 states]

    const float bias = dbias[d];
    const float Dd   = Dv[d];

    const float* Ab = A + d * N_ + NH * g;
    f8 A2v;
    A2v[0]=Ab[0]*LOG2E; A2v[1]=Ab[1]*LOG2E; A2v[2]=Ab[2]*LOG2E; A2v[3]=Ab[3]*LOG2E;
    A2v[4]=Ab[4]*LOG2E; A2v[5]=Ab[5]*LOG2E; A2v[6]=Ab[6]*LOG2E; A2v[7]=Ab[7]*LOG2E;

    const float* Bp = Bm + (size_t)b * (N_ * L_) + (size_t)(NH * g) * L_;
    const float* Cp = Cm + (size_t)b * (N_ * L_) + (size_t)(NH * g) * L_;
    const size_t chbase = (size_t)ch * L_;

    // ---- initial prefetch: my first chunk (c = w) ----
    const int off0 = w * LC + s * 4;
    f4 P0_dv = *(const f4*)(delta + chbase + off0);
    f4 P0_xv = *(const f4*)(x     + chbase + off0);
    f4 P0_B0 = *(const f4*)(Bp + 0 * L_ + off0);
    f4 P0_B1 = *(const f4*)(Bp + 1 * L_ + off0);
    f4 P0_B2 = *(const f4*)(Bp + 2 * L_ + off0);
    f4 P0_B3 = *(const f4*)(Bp + 3 * L_ + off0);
    f4 P0_B4 = *(const f4*)(Bp + 4 * L_ + off0);
    f4 P0_B5 = *(const f4*)(Bp + 5 * L_ + off0);
    f4 P0_B6 = *(const f4*)(Bp + 6 * L_ + off0);
    f4 P0_B7 = *(const f4*)(Bp + 7 * L_ + off0);
    f4 P1_dv, P1_xv, P1_B0, P1_B1, P1_B2, P1_B3, P1_B4, P1_B5, P1_B6, P1_B7;

#define SCAN_STEP_F(CTRL) \
    { \
        _Pragma("unroll") \
        for (int i = 0; i < NH; ++i) { \
            float Pp = updpp<CTRL, 0xF>(1.0f, F3v[i]); \
            float Sp = dpp0<CTRL, 0xF>(S3v[i]); \
            S3v[i] = fmaf(Sp, F3v[i], S3v[i]);   /* uses pre-update P */ \
            F3v[i] = F3v[i] * Pp; \
        } \
    }
#define SCAN_STEP_M(CTRL, RMASK) \
    { \
        _Pragma("unroll") \
        for (int i = 0; i < NH; ++i) { \
            float Pp = updpp<CTRL, RMASK>(1.0f, F3v[i]); \
            float Sp = updpp<CTRL, RMASK>(0.0f, S3v[i]); \
            S3v[i] = fmaf(Sp, F3v[i], S3v[i]); \
            F3v[i] = F3v[i] * Pp; \
        } \
    }
// fold: apply incoming carry, build h_in (state entering each lane's segment),
// publish my chunk-final state (lane s==31 of each half) to LDS slot[w].
#define FOLDCORE \
    { \
        _Pragma("unroll") \
        for (int i = 0; i < NH; ++i) { \
            hincv[i] = fmaf(cin[i], F3v[i], S3v[i]); \
            float hup = dpp0<DPP_WAVE_SHR1, 0xF>(hincv[i]); /* lane n <- n-1 */ \
            h[i] = (s == 0) ? cin[i] : hup;                 /* lanes 0 and 32 */ \
        } \
        if (s == 31) { \
            f4 lo = { hincv[0], hincv[1], hincv[2], hincv[3] }; \
            f4 hi = { hincv[4], hincv[5], hincv[6], hincv[7] }; \
            *(f4*)&carrybuf[w][g * NH]     = lo; \
            *(f4*)&carrybuf[w][g * NH + 4] = hi; \
        } \
    }
#define LDS_CIN(SLOT) \
    { \
        f4 lo = *(const f4*)&carrybuf[SLOT][g * NH]; \
        f4 hi = *(const f4*)&carrybuf[SLOT][g * NH + 4]; \
        cin[0]=lo.x; cin[1]=lo.y; cin[2]=lo.z; cin[3]=lo.w; \
        cin[4]=hi.x; cin[5]=hi.y; cin[6]=hi.z; cin[7]=hi.w; \
    }

#define ITER(k, CUR, NXT) { \
    const int c   = 2 * (k) + w;                 /* my chunk this iteration */ \
    const int off = c * LC + s * 4; \
    /* ======================= FRONT (carry-independent) ================== */ \
    /* C loads first so they're ready for the G/y0 section */ \
    f4 Cv0 = *(const f4*)(Cp + 0 * L_ + off); \
    f4 Cv1 = *(const f4*)(Cp + 1 * L_ + off); \
    f4 Cv2 = *(const f4*)(Cp + 2 * L_ + off); \
    f4 Cv3 = *(const f4*)(Cp + 3 * L_ + off); \
    f4 Cv4 = *(const f4*)(Cp + 4 * L_ + off); \
    f4 Cv5 = *(const f4*)(Cp + 5 * L_ + off); \
    f4 Cv6 = *(const f4*)(Cp + 6 * L_ + off); \
    f4 Cv7 = *(const f4*)(Cp + 7 * L_ + off); \
    float dt0 = softplus_f(CUR##_dv.x + bias); \
    float dt1 = softplus_f(CUR##_dv.y + bias); \
    float dt2 = softplus_f(CUR##_dv.z + bias); \
    float dt3 = softplus_f(CUR##_dv.w + bias); \
    float u0 = dt0 * CUR##_xv.x, u1 = dt1 * CUR##_xv.y; \
    float u2 = dt2 * CUR##_xv.z, u3 = dt3 * CUR##_xv.w; \
    f8 e0 = exp2v8(splat8(dt0) * A2v); \
    f8 e1 = exp2v8(splat8(dt1) * A2v); \
    f8 e2 = exp2v8(splat8(dt2) * A2v); \
    f8 e3 = exp2v8(splat8(dt3) * A2v); \
    f8 tB0 = {CUR##_B0.x,CUR##_B1.x,CUR##_B2.x,CUR##_B3.x,CUR##_B4.x,CUR##_B5.x,CUR##_B6.x,CUR##_B7.x}; \
    f8 tB1 = {CUR##_B0.y,CUR##_B1.y,CUR##_B2.y,CUR##_B3.y,CUR##_B4.y,CUR##_B5.y,CUR##_B6.y,CUR##_B7.y}; \
    f8 tB2 = {CUR##_B0.z,CUR##_B1.z,CUR##_B2.z,CUR##_B3.z,CUR##_B4.z,CUR##_B5.z,CUR##_B6.z,CUR##_B7.z}; \
    f8 tB3 = {CUR##_B0.w,CUR##_B1.w,CUR##_B2.w,CUR##_B3.w,CUR##_B4.w,CUR##_B5.w,CUR##_B6.w,CUR##_B7.w}; \
    /* pass 1: local prefix products F_j and partial states S_j (h_in = 0) */ \
    f8 S0v = splat8(u0) * tB0;             f8 F0v = e0; \
    f8 S1v = e1 * S0v + splat8(u1) * tB1;  f8 F1v = e1 * F0v; \
    f8 S2v = e2 * S1v + splat8(u2) * tB2;  f8 F2v = e2 * F1v; \
    f8 S3v = e3 * S2v + splat8(u3) * tB3;  f8 F3v = e3 * F2v; \
    /* carry-independent dot parts; G_j = C_j o F_j.  S0-2/F0-2/Cv die here */ \
    f8 SC0 = {Cv0.x,Cv1.x,Cv2.x,Cv3.x,Cv4.x,Cv5.x,Cv6.x,Cv7.x}; \
    f8 SC1 = {Cv0.y,Cv1.y,Cv2.y,Cv3.y,Cv4.y,Cv5.y,Cv6.y,Cv7.y}; \
    f8 SC2 = {Cv0.z,Cv1.z,Cv2.z,Cv3.z,Cv4.z,Cv5.z,Cv6.z,Cv7.z}; \
    f8 SC3 = {Cv0.w,Cv1.w,Cv2.w,Cv3.w,Cv4.w,Cv5.w,Cv6.w,Cv7.w}; \
    float y00 = dot8(SC0, S0v);  f8 G0 = SC0 * F0v; \
    float y10 = dot8(SC1, S1v);  f8 G1 = SC1 * F1v; \
    float y20 = dot8(SC2, S2v);  f8 G2 = SC2 * F2v; \
    /* width-32 inclusive scan of (F3v,S3v) in place */ \
    SCAN_STEP_F(DPP_ROW_SHR(1)) \
    SCAN_STEP_F(DPP_ROW_SHR(2)) \
    SCAN_STEP_F(DPP_ROW_SHR(4)) \
    SCAN_STEP_F(DPP_ROW_SHR(8)) \
    SCAN_STEP_M(DPP_ROW_BCAST15, 0xA) \
    /* ==================== carry exchange (2 barriers) =================== */ \
    f8 cin, h, hincv; \
    __syncthreads();                       /* A_k */ \
    if (w == 0) { \
        if ((k) == 0) { cin = splat8(0.0f); } else { LDS_CIN(1) } \
        FOLDCORE                            /* fold(2k), publish slot[0] */ \
    } \
    __syncthreads();                       /* B_k */ \
    if (w == 1) { \
        LDS_CIN(0) \
        FOLDCORE                            /* fold(2k+1), publish slot[1] */ \
    } \
    /* ============================ BACK ================================= */ \
    const int offn = (((k) == 7) ? c : c + 2) * LC + s * 4;  /* clamp tail */ \
    NXT##_dv = *(const f4*)(delta + chbase + offn); \
    NXT##_xv = *(const f4*)(x     + chbase + offn); \
    NXT##_B0 = *(const f4*)(Bp + 0 * L_ + offn); \
    NXT##_B1 = *(const f4*)(Bp + 1 * L_ + offn); \
    NXT##_B2 = *(const f4*)(Bp + 2 * L_ + offn); \
    NXT##_B3 = *(const f4*)(Bp + 3 * L_ + offn); \
    NXT##_B4 = *(const f4*)(Bp + 4 * L_ + offn); \
    NXT##_B5 = *(const f4*)(Bp + 5 * L_ + offn); \
    NXT##_B6 = *(const f4*)(Bp + 6 * L_ + offn); \
    NXT##_B7 = *(const f4*)(Bp + 7 * L_ + offn); \
    f4 zv = *(const f4*)(z + chbase + off); \
    float y0 = y00 + dot8(G0, h); \
    float y1 = y10 + dot8(G1, h); \
    float y2 = y20 + dot8(G2, h); \
    float y3 = dot8(SC3, hincv); \
    y0 += __shfl_xor(y0, 32, 64); \
    y1 += __shfl_xor(y1, 32, 64); \
    y2 += __shfl_xor(y2, 32, 64); \
    y3 += __shfl_xor(y3, 32, 64); \
    if (g == 0) { \
        float s0 = rcpf_(1.0f + exp2f_(-zv.x * LOG2E)); \
        float s1 = rcpf_(1.0f + exp2f_(-zv.y * LOG2E)); \
        float s2 = rcpf_(1.0f + exp2f_(-zv.z * LOG2E)); \
        float s3 = rcpf_(1.0f + exp2f_(-zv.w * LOG2E)); \
        f4 ov = { (y0 + CUR##_xv.x * Dd) * (zv.x * s0), \
                  (y1 + CUR##_xv.y * Dd) * (zv.y * s1), \
                  (y2 + CUR##_xv.z * Dd) * (zv.z * s2), \
                  (y3 + CUR##_xv.w * Dd) * (zv.w * s3) }; \
        *(f4*)(out + chbase + off) = ov; \
    } \
}

    for (int kk = 0; kk < 8; kk += 2) {
        ITER(kk,     P0, P1)
        ITER(kk + 1, P1, P0)
    }
}

extern "C" void kernel_launch(void* const* d_in, const int* in_sizes, int n_in,
                              void* d_out, int out_size, void* d_ws, size_t ws_size,
                              hipStream_t stream) {
    const float* x     = (const float*)d_in[0];
    const float* delta = (const float*)d_in[1];
    const float* A     = (const float*)d_in[2];
    const float* Bm    = (const float*)d_in[3];
    const float* Cm    = (const float*)d_in[4];
    const float* Dv    = (const float*)d_in[5];
    const float* z     = (const float*)d_in[6];
    const float* dbias = (const float*)d_in[7];
    float* out = (float*)d_out;

    dim3 grid(NCH);    // 3072 blocks = 2 waves = 1 channel each
    dim3 block(128);
    ssm_scan_kernel<<<grid, block, 0, stream>>>(x, delta, A, Bm, Cm, Dv, z, dbias, out);
}

// Round 6
// 364.355 us; speedup vs baseline: 1.4947x; 1.4947x over previous
//
#include <hip/hip_runtime.h>
#include <math.h>

#define B_  2
#define D_  1536
#define L_  2048
#define N_  16
#define NH  8                 // states per half-wave group
#define LC  128               // chunk length along L (32 segs x 4 elems)
#define NCHUNK (L_ / LC)      // 16 (8 per wave)
#define NCH (B_ * D_)         // 3072 channels
#define LOG2E 1.4426950408889634f
#define LN2   0.6931471805599453f

typedef float f4 __attribute__((ext_vector_type(4)));
typedef float f8 __attribute__((ext_vector_type(8)));

__device__ __forceinline__ float exp2f_(float v) { return __builtin_amdgcn_exp2f(v); }
__device__ __forceinline__ float log2f_(float v) { return __builtin_amdgcn_logf(v); }
__device__ __forceinline__ float rcpf_(float v)  { return __builtin_amdgcn_rcpf(v); }

__device__ __forceinline__ float softplus_f(float v) {
    float t = exp2f_(v * LOG2E);                   // e^v
    float r = LN2 * log2f_(1.0f + t);              // ln(1+e^v)
    return (v > 20.0f) ? v : r;
}
__device__ __forceinline__ f8 splat8(float v) { f8 r = {v,v,v,v,v,v,v,v}; return r; }
__device__ __forceinline__ f8 exp2v8(f8 a) {
    f8 r;
    r[0]=exp2f_(a[0]); r[1]=exp2f_(a[1]); r[2]=exp2f_(a[2]); r[3]=exp2f_(a[3]);
    r[4]=exp2f_(a[4]); r[5]=exp2f_(a[5]); r[6]=exp2f_(a[6]); r[7]=exp2f_(a[7]);
    return r;
}
__device__ __forceinline__ float dot8(f8 a, f8 b) {
    float p0 = fmaf(a[0], b[0], a[1]*b[1]);
    float p1 = fmaf(a[2], b[2], a[3]*b[3]);
    float p2 = fmaf(a[4], b[4], a[5]*b[5]);
    float p3 = fmaf(a[6], b[6], a[7]*b[7]);
    return (p0 + p1) + (p2 + p3);
}

#define DPP_ROW_SHR(N) (0x110 + (N))
#define DPP_ROW_BCAST15 0x142
#define DPP_WAVE_SHR1   0x138
template<int CTRL, int RMASK>
__device__ __forceinline__ float updpp(float old, float v) {
    return __int_as_float(__builtin_amdgcn_update_dpp(
        __float_as_int(old), __float_as_int(v), CTRL, RMASK, 0xF, false));
}
template<int CTRL, int RMASK>
__device__ __forceinline__ float dpp0(float v) {
    return __int_as_float(__builtin_amdgcn_update_dpp(
        0, __float_as_int(v), CTRL, RMASK, 0xF, true));
}

// Round 6: round-5's 2-wave chunk-alternating pipeline (sync scheme proven
// correct there) with the register economics fixed:
//  * NO register prefetch buffers (round-5 spill root cause: the 80-float
//    P0/P1 double-buffer was live ACROSS the barriers and loads cannot sink
//    past __syncthreads -> 150+ demanded regs vs the 85 cap -> scratch).
//    At 20 waves/CU the TLP hides the load latency the prefetch used to hide
//    at 3 waves/SIMD — that is the point of the 2-wave design.
//  * __launch_bounds__(128, 5): ~102-reg cap.  Cross-barrier live set is now
//    G0-2(24) + SC3(8) + F3/S3(16, die at fold) + y*0(3) + xv(4) + A2v(8)
//    + addressing ~ 75-80.  Fits with margin.
//  * carrybuf zero-initialized once -> no k==0 special case, uniform loop.
// Per iteration both waves run FRONT (loads, dt/exp, pass-1, DPP scan, G/y0
// dots) fully in parallel; the serial carry crosses waves via 16-float LDS
// slots with 2 barriers; each iteration retires TWO chunks.
// Spill tripwire: WRITE_SIZE != 24576 KB or FETCH >> 41 MB.
__global__ __launch_bounds__(128, 5)
void ssm_scan_kernel(const float* __restrict__ x,
                     const float* __restrict__ delta,
                     const float* __restrict__ A,
                     const float* __restrict__ Bm,
                     const float* __restrict__ Cm,
                     const float* __restrict__ Dv,
                     const float* __restrict__ z,
                     const float* __restrict__ dbias,
                     float* __restrict__ out)
{
    const int tid  = threadIdx.x;      // 0..127
    const int lane = tid & 63;
    const int s    = lane & 31;
    const int g    = (lane >> 5) & 1;  // half-wave state group
    const int w    = tid >> 6;         // wave id: chunk parity owner
    const int ch   = blockIdx.x;       // one channel per block
    const int b    = ch / D_;
    const int d    = ch - b * D_;

    __shared__ alignas(16) float carrybuf[2][N_];  // [chunk parity][16 states]
    if (tid < 2 * N_) ((float*)carrybuf)[tid] = 0.0f;

    const float bias = dbias[d];
    const float Dd   = Dv[d];

    const float* Ab = A + d * N_ + NH * g;
    f8 A2v;
    A2v[0]=Ab[0]*LOG2E; A2v[1]=Ab[1]*LOG2E; A2v[2]=Ab[2]*LOG2E; A2v[3]=Ab[3]*LOG2E;
    A2v[4]=Ab[4]*LOG2E; A2v[5]=Ab[5]*LOG2E; A2v[6]=Ab[6]*LOG2E; A2v[7]=Ab[7]*LOG2E;

    const float* Bp = Bm + (size_t)b * (N_ * L_) + (size_t)(NH * g) * L_;
    const float* Cp = Cm + (size_t)b * (N_ * L_) + (size_t)(NH * g) * L_;
    const size_t chbase = (size_t)ch * L_;

    __syncthreads();   // carrybuf zero-init visible to both waves

#define SCAN_STEP_F(CTRL) \
    { \
        _Pragma("unroll") \
        for (int i = 0; i < NH; ++i) { \
            float Pp = updpp<CTRL, 0xF>(1.0f, F3v[i]); \
            float Sp = dpp0<CTRL, 0xF>(S3v[i]); \
            S3v[i] = fmaf(Sp, F3v[i], S3v[i]);   /* uses pre-update P */ \
            F3v[i] = F3v[i] * Pp; \
        } \
    }
#define SCAN_STEP_M(CTRL, RMASK) \
    { \
        _Pragma("unroll") \
        for (int i = 0; i < NH; ++i) { \
            float Pp = updpp<CTRL, RMASK>(1.0f, F3v[i]); \
            float Sp = updpp<CTRL, RMASK>(0.0f, S3v[i]); \
            S3v[i] = fmaf(Sp, F3v[i], S3v[i]); \
            F3v[i] = F3v[i] * Pp; \
        } \
    }
// fold: apply incoming carry, build h (state entering each lane's segment),
// publish my chunk-final state (lane s==31 of each half) to LDS slot[w].
#define FOLDCORE \
    { \
        _Pragma("unroll") \
        for (int i = 0; i < NH; ++i) { \
            hincv[i] = fmaf(cin[i], F3v[i], S3v[i]); \
            float hup = dpp0<DPP_WAVE_SHR1, 0xF>(hincv[i]); /* lane n <- n-1 */ \
            h[i] = (s == 0) ? cin[i] : hup;                 /* lanes 0 and 32 */ \
        } \
        if (s == 31) { \
            f4 lo = { hincv[0], hincv[1], hincv[2], hincv[3] }; \
            f4 hi = { hincv[4], hincv[5], hincv[6], hincv[7] }; \
            *(f4*)&carrybuf[w][g * NH]     = lo; \
            *(f4*)&carrybuf[w][g * NH + 4] = hi; \
        } \
    }
#define LDS_CIN(SLOT) \
    { \
        f4 lo = *(const f4*)&carrybuf[SLOT][g * NH]; \
        f4 hi = *(const f4*)&carrybuf[SLOT][g * NH + 4]; \
        cin[0]=lo.x; cin[1]=lo.y; cin[2]=lo.z; cin[3]=lo.w; \
        cin[4]=hi.x; cin[5]=hi.y; cin[6]=hi.z; cin[7]=hi.w; \
    }

    for (int k = 0; k < NCHUNK / 2; ++k) {
        const int c   = 2 * k + w;                 // my chunk this iteration
        const int off = c * LC + s * 4;

        // ======================= FRONT (carry-independent) ==================
        f4 dv  = *(const f4*)(delta + chbase + off);
        f4 xv  = *(const f4*)(x     + chbase + off);
        f4 Bv0 = *(const f4*)(Bp + 0 * L_ + off);
        f4 Bv1 = *(const f4*)(Bp + 1 * L_ + off);
        f4 Bv2 = *(const f4*)(Bp + 2 * L_ + off);
        f4 Bv3 = *(const f4*)(Bp + 3 * L_ + off);
        f4 Bv4 = *(const f4*)(Bp + 4 * L_ + off);
        f4 Bv5 = *(const f4*)(Bp + 5 * L_ + off);
        f4 Bv6 = *(const f4*)(Bp + 6 * L_ + off);
        f4 Bv7 = *(const f4*)(Bp + 7 * L_ + off);
        f4 Cv0 = *(const f4*)(Cp + 0 * L_ + off);
        f4 Cv1 = *(const f4*)(Cp + 1 * L_ + off);
        f4 Cv2 = *(const f4*)(Cp + 2 * L_ + off);
        f4 Cv3 = *(const f4*)(Cp + 3 * L_ + off);
        f4 Cv4 = *(const f4*)(Cp + 4 * L_ + off);
        f4 Cv5 = *(const f4*)(Cp + 5 * L_ + off);
        f4 Cv6 = *(const f4*)(Cp + 6 * L_ + off);
        f4 Cv7 = *(const f4*)(Cp + 7 * L_ + off);

        float dt0 = softplus_f(dv.x + bias);
        float dt1 = softplus_f(dv.y + bias);
        float dt2 = softplus_f(dv.z + bias);
        float dt3 = softplus_f(dv.w + bias);
        float u0 = dt0 * xv.x, u1 = dt1 * xv.y;
        float u2 = dt2 * xv.z, u3 = dt3 * xv.w;

        f8 e0 = exp2v8(splat8(dt0) * A2v);
        f8 e1 = exp2v8(splat8(dt1) * A2v);
        f8 e2 = exp2v8(splat8(dt2) * A2v);
        f8 e3 = exp2v8(splat8(dt3) * A2v);

        f8 tB0 = {Bv0.x,Bv1.x,Bv2.x,Bv3.x,Bv4.x,Bv5.x,Bv6.x,Bv7.x};
        f8 tB1 = {Bv0.y,Bv1.y,Bv2.y,Bv3.y,Bv4.y,Bv5.y,Bv6.y,Bv7.y};
        f8 tB2 = {Bv0.z,Bv1.z,Bv2.z,Bv3.z,Bv4.z,Bv5.z,Bv6.z,Bv7.z};
        f8 tB3 = {Bv0.w,Bv1.w,Bv2.w,Bv3.w,Bv4.w,Bv5.w,Bv6.w,Bv7.w};

        // pass 1: local prefix products F_j and partial states S_j (h_in = 0)
        f8 S0v = splat8(u0) * tB0;             f8 F0v = e0;
        f8 S1v = e1 * S0v + splat8(u1) * tB1;  f8 F1v = e1 * F0v;
        f8 S2v = e2 * S1v + splat8(u2) * tB2;  f8 F2v = e2 * F1v;
        f8 S3v = e3 * S2v + splat8(u3) * tB3;  f8 F3v = e3 * F2v;

        // carry-independent dot parts; G_j = C_j o F_j.  S0-2/F0-2/Cv die here.
        f8 SC0 = {Cv0.x,Cv1.x,Cv2.x,Cv3.x,Cv4.x,Cv5.x,Cv6.x,Cv7.x};
        f8 SC1 = {Cv0.y,Cv1.y,Cv2.y,Cv3.y,Cv4.y,Cv5.y,Cv6.y,Cv7.y};
        f8 SC2 = {Cv0.z,Cv1.z,Cv2.z,Cv3.z,Cv4.z,Cv5.z,Cv6.z,Cv7.z};
        f8 SC3 = {Cv0.w,Cv1.w,Cv2.w,Cv3.w,Cv4.w,Cv5.w,Cv6.w,Cv7.w};
        float y00 = dot8(SC0, S0v);  f8 G0 = SC0 * F0v;
        float y10 = dot8(SC1, S1v);  f8 G1 = SC1 * F1v;
        float y20 = dot8(SC2, S2v);  f8 G2 = SC2 * F2v;

        // width-32 inclusive scan of (F3v,S3v) in place
        SCAN_STEP_F(DPP_ROW_SHR(1))
        SCAN_STEP_F(DPP_ROW_SHR(2))
        SCAN_STEP_F(DPP_ROW_SHR(4))
        SCAN_STEP_F(DPP_ROW_SHR(8))
        SCAN_STEP_M(DPP_ROW_BCAST15, 0xA)   // rows 1,3 only; rows 0,2 neutral

        // ==================== carry exchange (2 barriers) ===================
        f8 cin, h, hincv;
        __syncthreads();                       // A_k
        if (w == 0) {
            LDS_CIN(1)                          // w1's previous-iter carry (0 at k=0)
            FOLDCORE                            // fold chunk 2k, publish slot[0]
        }
        __syncthreads();                       // B_k
        if (w == 1) {
            LDS_CIN(0)
            FOLDCORE                            // fold chunk 2k+1, publish slot[1]
        }

        // ============================ BACK =================================
        f4 zv = *(const f4*)(z + chbase + off);
        float y0 = y00 + dot8(G0, h);
        float y1 = y10 + dot8(G1, h);
        float y2 = y20 + dot8(G2, h);
        float y3 = dot8(SC3, hincv);
        y0 += __shfl_xor(y0, 32, 64);
        y1 += __shfl_xor(y1, 32, 64);
        y2 += __shfl_xor(y2, 32, 64);
        y3 += __shfl_xor(y3, 32, 64);
        if (g == 0) {
            float s0 = rcpf_(1.0f + exp2f_(-zv.x * LOG2E));
            float s1 = rcpf_(1.0f + exp2f_(-zv.y * LOG2E));
            float s2 = rcpf_(1.0f + exp2f_(-zv.z * LOG2E));
            float s3 = rcpf_(1.0f + exp2f_(-zv.w * LOG2E));
            f4 ov = { (y0 + xv.x * Dd) * (zv.x * s0),
                      (y1 + xv.y * Dd) * (zv.y * s1),
                      (y2 + xv.z * Dd) * (zv.z * s2),
                      (y3 + xv.w * Dd) * (zv.w * s3) };
            *(f4*)(out + chbase + off) = ov;
        }
    }
}

extern "C" void kernel_launch(void* const* d_in, const int* in_sizes, int n_in,
                              void* d_out, int out_size, void* d_ws, size_t ws_size,
                              hipStream_t stream) {
    const float* x     = (const float*)d_in[0];
    const float* delta = (const float*)d_in[1];
    const float* A     = (const float*)d_in[2];
    const float* Bm    = (const float*)d_in[3];
    const float* Cm    = (const float*)d_in[4];
    const float* Dv    = (const float*)d_in[5];
    const float* z     = (const float*)d_in[6];
    const float* dbias = (const float*)d_in[7];
    float* out = (float*)d_out;

    dim3 grid(NCH);    // 3072 blocks = 2 waves = 1 channel each
    dim3 block(128);
    ssm_scan_kernel<<<grid, block, 0, stream>>>(x, delta, A, Bm, Cm, Dv, z, dbias, out);
}

// Round 7
// 170.427 us; speedup vs baseline: 3.1955x; 2.1379x over previous
//
#include <hip/hip_runtime.h>
#include <math.h>

#define B_  2
#define D_  1536
#define L_  2048
#define N_  16
#define NH  8                 // states per half-wave group
#define LC  128               // chunk length along L (32 segs x 4 elems)
#define NCHUNK (L_ / LC)      // 16 (8 per wave)
#define NCH (B_ * D_)         // 3072 channels
#define LOG2E 1.4426950408889634f
#define LN2   0.6931471805599453f

typedef float f4 __attribute__((ext_vector_type(4)));
typedef float f8 __attribute__((ext_vector_type(8)));

__device__ __forceinline__ float exp2f_(float v) { return __builtin_amdgcn_exp2f(v); }
__device__ __forceinline__ float log2f_(float v) { return __builtin_amdgcn_logf(v); }
__device__ __forceinline__ float rcpf_(float v)  { return __builtin_amdgcn_rcpf(v); }

__device__ __forceinline__ float softplus_f(float v) {
    float t = exp2f_(v * LOG2E);                   // e^v
    float r = LN2 * log2f_(1.0f + t);              // ln(1+e^v)
    return (v > 20.0f) ? v : r;
}
__device__ __forceinline__ f8 splat8(float v) { f8 r = {v,v,v,v,v,v,v,v}; return r; }
__device__ __forceinline__ f8 exp2v8(f8 a) {
    f8 r;
    r[0]=exp2f_(a[0]); r[1]=exp2f_(a[1]); r[2]=exp2f_(a[2]); r[3]=exp2f_(a[3]);
    r[4]=exp2f_(a[4]); r[5]=exp2f_(a[5]); r[6]=exp2f_(a[6]); r[7]=exp2f_(a[7]);
    return r;
}
__device__ __forceinline__ float dot8(f8 a, f8 b) {
    float p0 = fmaf(a[0], b[0], a[1]*b[1]);
    float p1 = fmaf(a[2], b[2], a[3]*b[3]);
    float p2 = fmaf(a[4], b[4], a[5]*b[5]);
    float p3 = fmaf(a[6], b[6], a[7]*b[7]);
    return (p0 + p1) + (p2 + p3);
}

#define DPP_ROW_SHR(N) (0x110 + (N))
#define DPP_ROW_BCAST15 0x142
#define DPP_WAVE_SHR1   0x138
template<int CTRL, int RMASK>
__device__ __forceinline__ float updpp(float old, float v) {
    return __int_as_float(__builtin_amdgcn_update_dpp(
        __float_as_int(old), __float_as_int(v), CTRL, RMASK, 0xF, false));
}
template<int CTRL, int RMASK>
__device__ __forceinline__ float dpp0(float v) {
    return __int_as_float(__builtin_amdgcn_update_dpp(
        0, __float_as_int(v), CTRL, RMASK, 0xF, true));
}

// Round 7: round-6's 2-wave chunk-alternating pipeline with the allocator
// fights resolved (rounds 5/6 spilled even at ~70 live floats — scorched-
// earth fallback, VGPR_Count 40/48):
//  * __launch_bounds__(128, 4): cap 128 (was 102/85).  FRONT's load burst +
//    transpose peak needs scheduling headroom UNDER the cap; 16 waves/CU is
//    still 2x round-4's TLP.
//  * NO f8 phi across the divergent fold (rule-#20 pattern): cin/h/hincv are
//    branch-LOCAL, and each wave's fold branch also computes its four y-dots,
//    so only 4 scalar y's (+ xv/zv) cross out of the divergent region.
//    G0-2/SC3/F3v/S3v die inside the fold.  Cross-barrier live (worst, w1):
//    G(24)+SC3(8)+F/S(16)+y*0(3)+xv,zv(8)+A2v(8) ~ 70 << 128.
//  * C loads issue AFTER pass-1 (their consumers SC/G/y*0 follow at once) so
//    the Bv and Cv bursts never overlap at register peak.
// Spill tripwire: WRITE_SIZE != 24576 KB or FETCH >> 41 MB.
__global__ __launch_bounds__(128, 4)
void ssm_scan_kernel(const float* __restrict__ x,
                     const float* __restrict__ delta,
                     const float* __restrict__ A,
                     const float* __restrict__ Bm,
                     const float* __restrict__ Cm,
                     const float* __restrict__ Dv,
                     const float* __restrict__ z,
                     const float* __restrict__ dbias,
                     float* __restrict__ out)
{
    const int tid  = threadIdx.x;      // 0..127
    const int lane = tid & 63;
    const int s    = lane & 31;
    const int g    = (lane >> 5) & 1;  // half-wave state group
    const int w    = tid >> 6;         // wave id: chunk parity owner
    const int ch   = blockIdx.x;       // one channel per block
    const int b    = ch / D_;
    const int d    = ch - b * D_;

    __shared__ alignas(16) float carrybuf[2][N_];  // [chunk parity][16 states]
    if (tid < 2 * N_) ((float*)carrybuf)[tid] = 0.0f;

    const float bias = dbias[d];
    const float Dd   = Dv[d];

    const float* Ab = A + d * N_ + NH * g;
    f8 A2v;
    A2v[0]=Ab[0]*LOG2E; A2v[1]=Ab[1]*LOG2E; A2v[2]=Ab[2]*LOG2E; A2v[3]=Ab[3]*LOG2E;
    A2v[4]=Ab[4]*LOG2E; A2v[5]=Ab[5]*LOG2E; A2v[6]=Ab[6]*LOG2E; A2v[7]=Ab[7]*LOG2E;

    const float* Bp = Bm + (size_t)b * (N_ * L_) + (size_t)(NH * g) * L_;
    const float* Cp = Cm + (size_t)b * (N_ * L_) + (size_t)(NH * g) * L_;
    const size_t chbase = (size_t)ch * L_;

    __syncthreads();   // carrybuf zero-init visible to both waves

#define SCAN_STEP_F(CTRL) \
    { \
        _Pragma("unroll") \
        for (int i = 0; i < NH; ++i) { \
            float Pp = updpp<CTRL, 0xF>(1.0f, F3v[i]); \
            float Sp = dpp0<CTRL, 0xF>(S3v[i]); \
            S3v[i] = fmaf(Sp, F3v[i], S3v[i]);   /* uses pre-update P */ \
            F3v[i] = F3v[i] * Pp; \
        } \
    }
#define SCAN_STEP_M(CTRL, RMASK) \
    { \
        _Pragma("unroll") \
        for (int i = 0; i < NH; ++i) { \
            float Pp = updpp<CTRL, RMASK>(1.0f, F3v[i]); \
            float Sp = updpp<CTRL, RMASK>(0.0f, S3v[i]); \
            S3v[i] = fmaf(Sp, F3v[i], S3v[i]); \
            F3v[i] = F3v[i] * Pp; \
        } \
    }
// Per-wave fold + output dots, entirely branch-local (no f8 escapes):
// read carry from SLOT, build h (state entering each lane's segment),
// publish my chunk-final state (lane s==31) to slot[w], compute y0..y3.
#define FOLD_AND_Y(SLOT) \
    { \
        f8 cin, h, hincv; \
        { \
            f4 lo = *(const f4*)&carrybuf[SLOT][g * NH]; \
            f4 hi = *(const f4*)&carrybuf[SLOT][g * NH + 4]; \
            cin[0]=lo.x; cin[1]=lo.y; cin[2]=lo.z; cin[3]=lo.w; \
            cin[4]=hi.x; cin[5]=hi.y; cin[6]=hi.z; cin[7]=hi.w; \
        } \
        _Pragma("unroll") \
        for (int i = 0; i < NH; ++i) { \
            hincv[i] = fmaf(cin[i], F3v[i], S3v[i]); \
            float hup = dpp0<DPP_WAVE_SHR1, 0xF>(hincv[i]); /* lane n <- n-1 */ \
            h[i] = (s == 0) ? cin[i] : hup;                 /* lanes 0 and 32 */ \
        } \
        if (s == 31) { \
            f4 lo = { hincv[0], hincv[1], hincv[2], hincv[3] }; \
            f4 hi = { hincv[4], hincv[5], hincv[6], hincv[7] }; \
            *(f4*)&carrybuf[w][g * NH]     = lo; \
            *(f4*)&carrybuf[w][g * NH + 4] = hi; \
        } \
        y0 = y00 + dot8(G0, h); \
        y1 = y10 + dot8(G1, h); \
        y2 = y20 + dot8(G2, h); \
        y3 = dot8(SC3, hincv); \
    }

    for (int k = 0; k < NCHUNK / 2; ++k) {
        const int c   = 2 * k + w;                 // my chunk this iteration
        const int off = c * LC + s * 4;

        // ======================= FRONT (carry-independent) ==================
        f4 dv  = *(const f4*)(delta + chbase + off);
        f4 xv  = *(const f4*)(x     + chbase + off);
        f4 zv  = *(const f4*)(z     + chbase + off);
        f4 Bv0 = *(const f4*)(Bp + 0 * L_ + off);
        f4 Bv1 = *(const f4*)(Bp + 1 * L_ + off);
        f4 Bv2 = *(const f4*)(Bp + 2 * L_ + off);
        f4 Bv3 = *(const f4*)(Bp + 3 * L_ + off);
        f4 Bv4 = *(const f4*)(Bp + 4 * L_ + off);
        f4 Bv5 = *(const f4*)(Bp + 5 * L_ + off);
        f4 Bv6 = *(const f4*)(Bp + 6 * L_ + off);
        f4 Bv7 = *(const f4*)(Bp + 7 * L_ + off);

        float dt0 = softplus_f(dv.x + bias);
        float dt1 = softplus_f(dv.y + bias);
        float dt2 = softplus_f(dv.z + bias);
        float dt3 = softplus_f(dv.w + bias);
        float u0 = dt0 * xv.x, u1 = dt1 * xv.y;
        float u2 = dt2 * xv.z, u3 = dt3 * xv.w;

        f8 e0 = exp2v8(splat8(dt0) * A2v);
        f8 e1 = exp2v8(splat8(dt1) * A2v);
        f8 e2 = exp2v8(splat8(dt2) * A2v);
        f8 e3 = exp2v8(splat8(dt3) * A2v);

        f8 tB0 = {Bv0.x,Bv1.x,Bv2.x,Bv3.x,Bv4.x,Bv5.x,Bv6.x,Bv7.x};
        f8 tB1 = {Bv0.y,Bv1.y,Bv2.y,Bv3.y,Bv4.y,Bv5.y,Bv6.y,Bv7.y};
        f8 tB2 = {Bv0.z,Bv1.z,Bv2.z,Bv3.z,Bv4.z,Bv5.z,Bv6.z,Bv7.z};
        f8 tB3 = {Bv0.w,Bv1.w,Bv2.w,Bv3.w,Bv4.w,Bv5.w,Bv6.w,Bv7.w};

        // pass 1: local prefix products F_j and partial states S_j (h_in = 0)
        f8 S0v = splat8(u0) * tB0;             f8 F0v = e0;
        f8 S1v = e1 * S0v + splat8(u1) * tB1;  f8 F1v = e1 * F0v;
        f8 S2v = e2 * S1v + splat8(u2) * tB2;  f8 F2v = e2 * F1v;
        f8 S3v = e3 * S2v + splat8(u3) * tB3;  f8 F3v = e3 * F2v;

        // C loads here: consumers (SC/G/y*0) immediately follow, so the Cv
        // burst never overlaps the Bv/e/tB register peak above.
        f4 Cv0 = *(const f4*)(Cp + 0 * L_ + off);
        f4 Cv1 = *(const f4*)(Cp + 1 * L_ + off);
        f4 Cv2 = *(const f4*)(Cp + 2 * L_ + off);
        f4 Cv3 = *(const f4*)(Cp + 3 * L_ + off);
        f4 Cv4 = *(const f4*)(Cp + 4 * L_ + off);
        f4 Cv5 = *(const f4*)(Cp + 5 * L_ + off);
        f4 Cv6 = *(const f4*)(Cp + 6 * L_ + off);
        f4 Cv7 = *(const f4*)(Cp + 7 * L_ + off);
        f8 SC0 = {Cv0.x,Cv1.x,Cv2.x,Cv3.x,Cv4.x,Cv5.x,Cv6.x,Cv7.x};
        f8 SC1 = {Cv0.y,Cv1.y,Cv2.y,Cv3.y,Cv4.y,Cv5.y,Cv6.y,Cv7.y};
        f8 SC2 = {Cv0.z,Cv1.z,Cv2.z,Cv3.z,Cv4.z,Cv5.z,Cv6.z,Cv7.z};
        f8 SC3 = {Cv0.w,Cv1.w,Cv2.w,Cv3.w,Cv4.w,Cv5.w,Cv6.w,Cv7.w};
        float y00 = dot8(SC0, S0v);  f8 G0 = SC0 * F0v;
        float y10 = dot8(SC1, S1v);  f8 G1 = SC1 * F1v;
        float y20 = dot8(SC2, S2v);  f8 G2 = SC2 * F2v;

        // width-32 inclusive scan of (F3v,S3v) in place
        SCAN_STEP_F(DPP_ROW_SHR(1))
        SCAN_STEP_F(DPP_ROW_SHR(2))
        SCAN_STEP_F(DPP_ROW_SHR(4))
        SCAN_STEP_F(DPP_ROW_SHR(8))
        SCAN_STEP_M(DPP_ROW_BCAST15, 0xA)   // rows 1,3 only; rows 0,2 neutral

        // ============ carry exchange (2 barriers) + per-wave fold ==========
        float y0, y1, y2, y3;                  // only scalars escape the folds
        __syncthreads();                       // A_k
        if (w == 0) {
            FOLD_AND_Y(1)                       // w1's prev-iter carry (0 at k=0)
        }
        __syncthreads();                       // B_k
        if (w == 1) {
            FOLD_AND_Y(0)                       // w0's this-iter carry
        }

        // ============================ BACK =================================
        y0 += __shfl_xor(y0, 32, 64);
        y1 += __shfl_xor(y1, 32, 64);
        y2 += __shfl_xor(y2, 32, 64);
        y3 += __shfl_xor(y3, 32, 64);
        if (g == 0) {
            float s0 = rcpf_(1.0f + exp2f_(-zv.x * LOG2E));
            float s1 = rcpf_(1.0f + exp2f_(-zv.y * LOG2E));
            float s2 = rcpf_(1.0f + exp2f_(-zv.z * LOG2E));
            float s3 = rcpf_(1.0f + exp2f_(-zv.w * LOG2E));
            f4 ov = { (y0 + xv.x * Dd) * (zv.x * s0),
                      (y1 + xv.y * Dd) * (zv.y * s1),
                      (y2 + xv.z * Dd) * (zv.z * s2),
                      (y3 + xv.w * Dd) * (zv.w * s3) };
            *(f4*)(out + chbase + off) = ov;
        }
    }
}

extern "C" void kernel_launch(void* const* d_in, const int* in_sizes, int n_in,
                              void* d_out, int out_size, void* d_ws, size_t ws_size,
                              hipStream_t stream) {
    const float* x     = (const float*)d_in[0];
    const float* delta = (const float*)d_in[1];
    const float* A     = (const float*)d_in[2];
    const float* Bm    = (const float*)d_in[3];
    const float* Cm    = (const float*)d_in[4];
    const float* Dv    = (const float*)d_in[5];
    const float* z     = (const float*)d_in[6];
    const float* dbias = (const float*)d_in[7];
    float* out = (float*)d_out;

    dim3 grid(NCH);    // 3072 blocks = 2 waves = 1 channel each
    dim3 block(128);
    ssm_scan_kernel<<<grid, block, 0, stream>>>(x, delta, A, Bm, Cm, Dv, z, dbias, out);
}

// Round 8
// 162.069 us; speedup vs baseline: 3.3602x; 1.0516x over previous
//
#include <hip/hip_runtime.h>
#include <math.h>

#define B_  2
#define D_  1536
#define L_  2048
#define N_  16
#define NH  8                 // states per half-wave
#define LC  128               // chunk length along L (32 segs x 4 elems)
#define NCHUNK (L_ / LC)      // 16
#define NCH (B_ * D_)         // 3072 channels
#define LOG2E 1.4426950408889634f
#define LN2   0.6931471805599453f

typedef float f4 __attribute__((ext_vector_type(4)));
typedef float f8 __attribute__((ext_vector_type(8)));

__device__ __forceinline__ float exp2f_(float v) { return __builtin_amdgcn_exp2f(v); }
__device__ __forceinline__ float log2f_(float v) { return __builtin_amdgcn_logf(v); }
__device__ __forceinline__ float rcpf_(float v)  { return __builtin_amdgcn_rcpf(v); }

__device__ __forceinline__ float softplus_f(float v) {
    float t = exp2f_(v * LOG2E);                   // e^v
    float r = LN2 * log2f_(1.0f + t);              // ln(1+e^v)
    return (v > 20.0f) ? v : r;
}
__device__ __forceinline__ f8 splat8(float v) { f8 r = {v,v,v,v,v,v,v,v}; return r; }
__device__ __forceinline__ f8 exp2v8(f8 a) {
    f8 r;
    r[0]=exp2f_(a[0]); r[1]=exp2f_(a[1]); r[2]=exp2f_(a[2]); r[3]=exp2f_(a[3]);
    r[4]=exp2f_(a[4]); r[5]=exp2f_(a[5]); r[6]=exp2f_(a[6]); r[7]=exp2f_(a[7]);
    return r;
}
__device__ __forceinline__ float dot8(f8 a, f8 b) {
    float p0 = fmaf(a[0], b[0], a[1]*b[1]);
    float p1 = fmaf(a[2], b[2], a[3]*b[3]);
    float p2 = fmaf(a[4], b[4], a[5]*b[5]);
    float p3 = fmaf(a[6], b[6], a[7]*b[7]);
    return (p0 + p1) + (p2 + p3);
}

#define DPP_WAVE_SHR1   0x138
template<int CTRL, int RMASK>
__device__ __forceinline__ float dpp0(float v) {
    return __int_as_float(__builtin_amdgcn_update_dpp(
        0, __float_as_int(v), CTRL, RMASK, 0xF, true));
}

// Round 8 = round-4's proven 76us structure (1 wave/channel, delta/x/B
// register-prefetched one chunk ahead, F/S pass-1 form) with the width-32
// scan re-expressed as FUSED DPP ARITHMETIC via inline asm.
//
// Why asm: GFX9 DPP on VOP2 with bound_ctrl UNSET (omitted; beware LLVM's
// legacy "bound_ctrl:0" actually SETS the 0-fill bit) write-predicates
// invalid lanes — dest keeps its value.  That is exactly the scan identity:
//   v_fmac_f32_dpp S, S(row_shr:N), F   ; valid: S += shr(S)*F; invalid: S
//   v_mul_f32_dpp  F, F(row_shr:N), F   ; valid: F  = shr(F)*F; invalid: F
// 2 instrs/state/step vs 3-4 for the update_dpp+identity form (the intrinsic
// cannot express predicated-write: old is a data operand, F*=updpp(old=F)
// would square F on invalid lanes).  Masked bcast15 step fuses the same way
// with row_mask:0xa.  Scan: ~120-160 -> 80 instrs/chunk (~10-17% of body).
// Ordering: fmac reads pre-update F (input constraint) before the mul
// writes it ("+v") — WAR/RAW enforced by register dependencies; pure VALU
// asm, no waitcnt interaction, not volatile so the scheduler stays free.
// Cross-round evidence for "cut instructions, not stalls": busy-cycle totals
// constant (43-46 us-equiv) across 1-wave/2-wave/prefetch variants; duration
// tracks instruction count with a ~45% stall floor.
// Spill tripwire: WRITE_SIZE != 24576 KB.  Correctness tripwire: absmax
// (DPP semantics error would blow it up).
__global__ __launch_bounds__(64, 3)
void ssm_scan_kernel(const float* __restrict__ x,
                     const float* __restrict__ delta,
                     const float* __restrict__ A,
                     const float* __restrict__ Bm,
                     const float* __restrict__ Cm,
                     const float* __restrict__ Dv,
                     const float* __restrict__ z,
                     const float* __restrict__ dbias,
                     float* __restrict__ out)
{
    const int lane = threadIdx.x;      // 0..63
    const int s    = lane & 31;
    const int g    = lane >> 5;
    const int ch   = blockIdx.x;       // one channel per wave
    const int b    = ch / D_;
    const int d    = ch - b * D_;

    const float bias = dbias[d];
    const float Dd   = Dv[d];

    const float* Ab = A + d * N_ + NH * g;
    f8 A2v;
    A2v[0]=Ab[0]*LOG2E; A2v[1]=Ab[1]*LOG2E; A2v[2]=Ab[2]*LOG2E; A2v[3]=Ab[3]*LOG2E;
    A2v[4]=Ab[4]*LOG2E; A2v[5]=Ab[5]*LOG2E; A2v[6]=Ab[6]*LOG2E; A2v[7]=Ab[7]*LOG2E;

    const float* Bp = Bm + (size_t)b * (N_ * L_) + (size_t)(NH * g) * L_;
    const float* Cp = Cm + (size_t)b * (N_ * L_) + (size_t)(NH * g) * L_;
    const size_t chbase = (size_t)ch * L_;

    f8 carry = splat8(0.0f);

    // ---- early-consumed operands (delta, x, B) double-buffered 1 chunk ahead ----
    f4 P0_dv = *(const f4*)(delta + chbase + s * 4);
    f4 P0_xv = *(const f4*)(x     + chbase + s * 4);
    f4 P0_B0 = *(const f4*)(Bp + 0 * L_ + s * 4);
    f4 P0_B1 = *(const f4*)(Bp + 1 * L_ + s * 4);
    f4 P0_B2 = *(const f4*)(Bp + 2 * L_ + s * 4);
    f4 P0_B3 = *(const f4*)(Bp + 3 * L_ + s * 4);
    f4 P0_B4 = *(const f4*)(Bp + 4 * L_ + s * 4);
    f4 P0_B5 = *(const f4*)(Bp + 5 * L_ + s * 4);
    f4 P0_B6 = *(const f4*)(Bp + 6 * L_ + s * 4);
    f4 P0_B7 = *(const f4*)(Bp + 7 * L_ + s * 4);
    f4 P1_dv, P1_xv, P1_B0, P1_B1, P1_B2, P1_B3, P1_B4, P1_B5, P1_B6, P1_B7;

// Fused-DPP scan steps (see header comment).  bound_ctrl deliberately omitted.
#define SCAN_ASM_STEP(SHR) \
    { \
        _Pragma("unroll") \
        for (int i = 0; i < NH; ++i) { \
            asm("v_fmac_f32_dpp %0, %0, %1 row_shr:" #SHR " row_mask:0xf bank_mask:0xf" \
                : "+v"(S3v[i]) : "v"(F3v[i])); \
            asm("v_mul_f32_dpp %0, %0, %0 row_shr:" #SHR " row_mask:0xf bank_mask:0xf" \
                : "+v"(F3v[i])); \
        } \
    }
#define SCAN_ASM_BCAST15 \
    { \
        _Pragma("unroll") \
        for (int i = 0; i < NH; ++i) { \
            asm("v_fmac_f32_dpp %0, %0, %1 row_bcast:15 row_mask:0xa bank_mask:0xf" \
                : "+v"(S3v[i]) : "v"(F3v[i])); \
            asm("v_mul_f32_dpp %0, %0, %0 row_bcast:15 row_mask:0xa bank_mask:0xf" \
                : "+v"(F3v[i])); \
        } \
    }

#define BODY(c, CUR, NXT) { \
    const int off  = (c) * LC + s * 4; \
    /* clamp: last chunk re-prefetches ITS OWN data (L1-hot) instead of wrapping */ \
    const int offn = (((c) == NCHUNK - 1) ? (c) : (c) + 1) * LC + s * 4; \
    /* ---- next-chunk early-use prefetch FIRST (dv retires soonest) ---- */ \
    NXT##_dv = *(const f4*)(delta + chbase + offn); \
    NXT##_xv = *(const f4*)(x     + chbase + offn); \
    NXT##_B0 = *(const f4*)(Bp + 0 * L_ + offn); \
    NXT##_B1 = *(const f4*)(Bp + 1 * L_ + offn); \
    NXT##_B2 = *(const f4*)(Bp + 2 * L_ + offn); \
    NXT##_B3 = *(const f4*)(Bp + 3 * L_ + offn); \
    NXT##_B4 = *(const f4*)(Bp + 4 * L_ + offn); \
    NXT##_B5 = *(const f4*)(Bp + 5 * L_ + offn); \
    NXT##_B6 = *(const f4*)(Bp + 6 * L_ + offn); \
    NXT##_B7 = *(const f4*)(Bp + 7 * L_ + offn); \
    /* ---- current-chunk late-use loads (L2-hot, ~1000cy of cover) ---- */ \
    f4 zv  = *(const f4*)(z + chbase + off); \
    f4 Cv0 = *(const f4*)(Cp + 0 * L_ + off); \
    f4 Cv1 = *(const f4*)(Cp + 1 * L_ + off); \
    f4 Cv2 = *(const f4*)(Cp + 2 * L_ + off); \
    f4 Cv3 = *(const f4*)(Cp + 3 * L_ + off); \
    f4 Cv4 = *(const f4*)(Cp + 4 * L_ + off); \
    f4 Cv5 = *(const f4*)(Cp + 5 * L_ + off); \
    f4 Cv6 = *(const f4*)(Cp + 6 * L_ + off); \
    f4 Cv7 = *(const f4*)(Cp + 7 * L_ + off); \
    /* ---- dt / u ---- */ \
    float dt0 = softplus_f(CUR##_dv.x + bias); \
    float dt1 = softplus_f(CUR##_dv.y + bias); \
    float dt2 = softplus_f(CUR##_dv.z + bias); \
    float dt3 = softplus_f(CUR##_dv.w + bias); \
    float u0 = dt0 * CUR##_xv.x, u1 = dt1 * CUR##_xv.y; \
    float u2 = dt2 * CUR##_xv.z, u3 = dt3 * CUR##_xv.w; \
    /* ---- per-element deltaA vectors ---- */ \
    f8 e0 = exp2v8(splat8(dt0) * A2v); \
    f8 e1 = exp2v8(splat8(dt1) * A2v); \
    f8 e2 = exp2v8(splat8(dt2) * A2v); \
    f8 e3 = exp2v8(splat8(dt3) * A2v); \
    /* ---- transpose B/C fragments to per-j state-vectors ---- */ \
    f8 tB0 = {CUR##_B0.x,CUR##_B1.x,CUR##_B2.x,CUR##_B3.x,CUR##_B4.x,CUR##_B5.x,CUR##_B6.x,CUR##_B7.x}; \
    f8 tB1 = {CUR##_B0.y,CUR##_B1.y,CUR##_B2.y,CUR##_B3.y,CUR##_B4.y,CUR##_B5.y,CUR##_B6.y,CUR##_B7.y}; \
    f8 tB2 = {CUR##_B0.z,CUR##_B1.z,CUR##_B2.z,CUR##_B3.z,CUR##_B4.z,CUR##_B5.z,CUR##_B6.z,CUR##_B7.z}; \
    f8 tB3 = {CUR##_B0.w,CUR##_B1.w,CUR##_B2.w,CUR##_B3.w,CUR##_B4.w,CUR##_B5.w,CUR##_B6.w,CUR##_B7.w}; \
    f8 SC0 = {Cv0.x,Cv1.x,Cv2.x,Cv3.x,Cv4.x,Cv5.x,Cv6.x,Cv7.x}; \
    f8 SC1 = {Cv0.y,Cv1.y,Cv2.y,Cv3.y,Cv4.y,Cv5.y,Cv6.y,Cv7.y}; \
    f8 SC2 = {Cv0.z,Cv1.z,Cv2.z,Cv3.z,Cv4.z,Cv5.z,Cv6.z,Cv7.z}; \
    f8 SC3 = {Cv0.w,Cv1.w,Cv2.w,Cv3.w,Cv4.w,Cv5.w,Cv6.w,Cv7.w}; \
    /* ---- pass 1: local scan keeping prefix products/states ---- */ \
    f8 S0v = splat8(u0) * tB0;             f8 F0v = e0; \
    f8 S1v = e1 * S0v + splat8(u1) * tB1;  f8 F1v = e1 * F0v; \
    f8 S2v = e2 * S1v + splat8(u2) * tB2;  f8 F2v = e2 * F1v; \
    f8 S3v = e3 * S2v + splat8(u3) * tB3;  f8 F3v = e3 * F2v; \
    /* ---- width-32 inclusive scan of (F3v,S3v): fused DPP asm ---- */ \
    SCAN_ASM_STEP(1) \
    SCAN_ASM_STEP(2) \
    SCAN_ASM_STEP(4) \
    SCAN_ASM_STEP(8) \
    SCAN_ASM_BCAST15   /* rows 1,3 only; rows 0,2 not written (mask 0xA) */ \
    /* ---- fold chunk carry; h_in entering this lane's segment ---- */ \
    f8 h; f8 hincv; \
    _Pragma("unroll") \
    for (int i = 0; i < NH; ++i) { \
        hincv[i] = fmaf(carry[i], F3v[i], S3v[i]);          /* state after elem 3 */ \
        float hup = dpp0<DPP_WAVE_SHR1, 0xF>(hincv[i]);     /* lane n <- n-1 */ \
        h[i] = (s == 0) ? carry[i] : hup; \
        carry[i] = __shfl(hincv[i], 31, 32);                /* broadcast within half */ \
    } \
    /* ---- pass 2: independent per-element states; y_j = <h_j, C_j> ---- */ \
    f8 t0 = F0v * h + S0v;  float y0 = dot8(t0, SC0); \
    f8 t1 = F1v * h + S1v;  float y1 = dot8(t1, SC1); \
    f8 t2 = F2v * h + S2v;  float y2 = dot8(t2, SC2); \
    float y3 = dot8(hincv, SC3); \
    /* ---- combine the two state-halves; epilogue; half-wave store ---- */ \
    y0 += __shfl_xor(y0, 32, 64); \
    y1 += __shfl_xor(y1, 32, 64); \
    y2 += __shfl_xor(y2, 32, 64); \
    y3 += __shfl_xor(y3, 32, 64); \
    if (g == 0) { \
        float s0 = rcpf_(1.0f + exp2f_(-zv.x * LOG2E)); \
        float s1 = rcpf_(1.0f + exp2f_(-zv.y * LOG2E)); \
        float s2 = rcpf_(1.0f + exp2f_(-zv.z * LOG2E)); \
        float s3 = rcpf_(1.0f + exp2f_(-zv.w * LOG2E)); \
        f4 ov = { (y0 + CUR##_xv.x * Dd) * (zv.x * s0), \
                  (y1 + CUR##_xv.y * Dd) * (zv.y * s1), \
                  (y2 + CUR##_xv.z * Dd) * (zv.z * s2), \
                  (y3 + CUR##_xv.w * Dd) * (zv.w * s3) }; \
        *(f4*)(out + chbase + off) = ov; \
    } \
}

    for (int cc = 0; cc < NCHUNK; cc += 2) {
        BODY(cc,     P0, P1)
        BODY(cc + 1, P1, P0)
    }
}

extern "C" void kernel_launch(void* const* d_in, const int* in_sizes, int n_in,
                              void* d_out, int out_size, void* d_ws, size_t ws_size,
                              hipStream_t stream) {
    const float* x     = (const float*)d_in[0];
    const float* delta = (const float*)d_in[1];
    const float* A     = (const float*)d_in[2];
    const float* Bm    = (const float*)d_in[3];
    const float* Cm    = (const float*)d_in[4];
    const float* Dv    = (const float*)d_in[5];
    const float* z     = (const float*)d_in[6];
    const float* dbias = (const float*)d_in[7];
    float* out = (float*)d_out;

    dim3 grid(NCH);    // 3072 blocks = 1 wave = 1 channel each
    dim3 block(64);
    ssm_scan_kernel<<<grid, block, 0, stream>>>(x, delta, A, Bm, Cm, Dv, z, dbias, out);
}